// Round 9
// baseline (2627.318 us; speedup 1.0000x reference)
//
#include <hip/hip_runtime.h>

typedef unsigned int u32;

#define T_LEN 2048
#define NEG (-10000.0f)
#define WSCALE 2032.0f
#define HSCALE 127.0f
#define SCALE_INV (1.0f / (2032.0f * 127.0f))

// ---------- helpers ----------
__device__ __forceinline__ int sdot4(u32 a, u32 b, int c) {
#if __has_builtin(__builtin_amdgcn_sdot4)
  return __builtin_amdgcn_sdot4((int)a, (int)b, c, false);
#else
  int r = c;
  r += (int)(signed char)(a)       * (int)(signed char)(b);
  r += (int)(signed char)(a >> 8)  * (int)(signed char)(b >> 8);
  r += (int)(signed char)(a >> 16) * (int)(signed char)(b >> 16);
  r += (int)(signed char)(a >> 24) * (int)(signed char)(b >> 24);
  return r;
#endif
}

__device__ __forceinline__ u32 rdlane_u32(u32 v, int lane) {
#if __has_builtin(__builtin_amdgcn_readlane)
  return (u32)__builtin_amdgcn_readlane((int)v, lane);
#else
  return (u32)__shfl((int)v, lane);
#endif
}

__device__ __forceinline__ float rdlane_f32(float v, int lane) {
  return __builtin_bit_cast(float, rdlane_u32(__builtin_bit_cast(u32, v), lane));
}

// Raw barrier: LDS-drain only, no vmcnt(0) drain.
__device__ __forceinline__ void block_sync_lds() {
  asm volatile("s_waitcnt lgkmcnt(0)" ::: "memory");
  __builtin_amdgcn_s_barrier();
}

// Empty asm "pin" on SCALAR u32 lvalues (supported tie form): forces these 8
// dwords to be arch-VGPR-resident here; AGPR residency would cost copies.
#define PIN8(a,b,c_,d_,e,f,g_,h_)                                     \
  asm volatile("" : "+v"(a), "+v"(b), "+v"(c_), "+v"(d_),             \
                    "+v"(e), "+v"(f), "+v"(g_), "+v"(h_))
#define PINROW(W, base) \
  PIN8(W[base+0], W[base+1], W[base+2], W[base+3],                    \
       W[base+4], W[base+5], W[base+6], W[base+7])

// ---------- kernel 1: pack Whh (both dirs) into int8 quads ----------
// Cell c, gate G (0=i,1=f,2=g,3=o): source row r = G*256+c.
// dest uint4 index: ((d*4+G)*16 + q4)*256 + c
__global__ void pack_whh_i8(const float* __restrict__ Wf,
                            const float* __restrict__ Wb,
                            u32* __restrict__ WP) {
  int idx = blockIdx.x * 256 + threadIdx.x;   // < 131072
  int d   = idx >> 16;
  int G   = (idx >> 14) & 3;
  int q4  = (idx >> 10) & 15;
  int c   = (idx >> 2) & 255;
  int j   = idx & 3;
  const float* W = d ? Wb : Wf;
  float4 v = *(const float4*)&W[(G * 256 + c) * 256 + q4 * 16 + j * 4];
  int b0 = (int)rintf(fminf(fmaxf(v.x * WSCALE, -127.f), 127.f));
  int b1 = (int)rintf(fminf(fmaxf(v.y * WSCALE, -127.f), 127.f));
  int b2 = (int)rintf(fminf(fmaxf(v.z * WSCALE, -127.f), 127.f));
  int b3 = (int)rintf(fminf(fmaxf(v.w * WSCALE, -127.f), 127.f));
  WP[(((d * 4 + G) * 16 + q4) * 256 + c) * 4 + j] =
      (u32)(b0 & 255) | ((u32)(b1 & 255) << 8) |
      ((u32)(b2 & 255) << 16) | ((u32)(b3 & 255) << 24);
}

// ---------- kernel 2: embedding gather ----------
__global__ void gather_kernel(const int* __restrict__ words,
                              const float* __restrict__ embed,
                              float* __restrict__ xs) {
  int t = blockIdx.x;
  int k = threadIdx.x;
  xs[t * 256 + k] = embed[(size_t)words[t] * 256 + k];
}

// ---------- kernel 3: XW[d][t][c][G] = xs[t]·Wih_d[G*256+c] + bih + bhh ----------
// Output layout [t][cell][gate] so lstm_seq reads ONE float4 per step.
__global__ __launch_bounds__(256) void gemm_xw(
    const float* __restrict__ xs,
    const float* __restrict__ Wf, const float* __restrict__ Wb,
    const float* __restrict__ bihf, const float* __restrict__ bhhf,
    const float* __restrict__ bihb, const float* __restrict__ bhhb,
    float* __restrict__ XW) {
  __shared__ float lx[32 * 256];
  __shared__ float lw[32 * 132];
  const int tid = threadIdx.x;
  const int t0 = blockIdx.x * 32;
  const int g0 = blockIdx.y * 128;
  const int d  = blockIdx.z;
  const float* W = d ? Wb : Wf;

  #pragma unroll 4
  for (int r = 0; r < 32; ++r) lx[r * 256 + tid] = xs[(t0 + r) * 256 + tid];

  const int tg = tid & 31, tt = tid >> 5;
  float acc[4][4] = {};

  for (int kc = 0; kc < 8; ++kc) {
    __syncthreads();
    #pragma unroll
    for (int r2 = 0; r2 < 16; ++r2) {
      int gg = r2 * 8 + (tid >> 5);
      int k  = tid & 31;
      lw[k * 132 + gg] = W[(g0 + gg) * 256 + kc * 32 + k];
    }
    __syncthreads();
    #pragma unroll
    for (int k = 0; k < 32; ++k) {
      float4 wv = *(const float4*)&lw[k * 132 + tg * 4];
      #pragma unroll
      for (int a = 0; a < 4; ++a) {
        float xa = lx[(tt * 4 + a) * 256 + kc * 32 + k];
        acc[a][0] = fmaf(xa, wv.x, acc[a][0]);
        acc[a][1] = fmaf(xa, wv.y, acc[a][1]);
        acc[a][2] = fmaf(xa, wv.z, acc[a][2]);
        acc[a][3] = fmaf(xa, wv.w, acc[a][3]);
      }
    }
  }
  const float* bih = d ? bihb : bihf;
  const float* bhh = d ? bhhb : bhhf;
  int gcol = g0 + tg * 4;
  float bb[4];
  #pragma unroll
  for (int j = 0; j < 4; ++j) bb[j] = bih[gcol + j] + bhh[gcol + j];
  #pragma unroll
  for (int a = 0; a < 4; ++a) {
    size_t trow = (size_t)d * T_LEN + t0 + tt * 4 + a;
    #pragma unroll
    for (int j = 0; j < 4; ++j) {
      int g = gcol + j;
      XW[trow * 1024 + (g & 255) * 4 + (g >> 8)] = acc[a][j] + bb[j];
    }
  }
}

// ---------- kernel 4: the sequential bidirectional LSTM (int8 dot4) ----------
// grid = 2 (d), block = 256; thread c owns ALL FOUR gate rows of cell c.
// Gates i,f,g (192 u32) pinned to arch VGPRs each step (scalar "+v" ties);
// gate o (64) left to the allocator (AGPR). One barrier/step, H8 dbuf.
__global__ void __launch_bounds__(256)
__attribute__((amdgpu_waves_per_eu(1, 1)))
lstm_seq(
    const float* __restrict__ XW, float* __restrict__ HS,
    const u32* __restrict__ wpack,
    const float* __restrict__ h0, const float* __restrict__ c0) {
  __shared__ u32 H8[2][64];     // double-buffered packed h (256 x i8)
  const int tid = threadIdx.x;  // cell index c
  const int d = blockIdx.x;
  const int lane = tid & 63;

  u32 wI[64], wF[64], wG[64], wO[64];
  {
    const uint4* wr = (const uint4*)wpack;
    #pragma unroll
    for (int q4 = 0; q4 < 16; ++q4) {
      uint4 t;
      t = wr[((d * 4 + 0) * 16 + q4) * 256 + tid];
      wI[q4*4+0] = t.x; wI[q4*4+1] = t.y; wI[q4*4+2] = t.z; wI[q4*4+3] = t.w;
      t = wr[((d * 4 + 1) * 16 + q4) * 256 + tid];
      wF[q4*4+0] = t.x; wF[q4*4+1] = t.y; wF[q4*4+2] = t.z; wF[q4*4+3] = t.w;
      t = wr[((d * 4 + 2) * 16 + q4) * 256 + tid];
      wG[q4*4+0] = t.x; wG[q4*4+1] = t.y; wG[q4*4+2] = t.z; wG[q4*4+3] = t.w;
      t = wr[((d * 4 + 3) * 16 + q4) * 256 + tid];
      wO[q4*4+0] = t.x; wO[q4*4+1] = t.y; wO[q4*4+2] = t.z; wO[q4*4+3] = t.w;
    }
  }

  float c = c0[d * 256 + tid];
  float h = h0[d * 256 + tid];
  {
    int hi = (int)rintf(fminf(fmaxf(h, -1.0f), 1.0f) * HSCALE);
    ((unsigned char*)&H8[0][0])[tid] = (unsigned char)(hi & 255);
  }
  block_sync_lds();
  u32 hA = H8[0][lane];

  const int delta = d ? -1024 : 1024;
  const float* xwp = XW + ((size_t)d * T_LEN + (d ? (T_LEN - 1) : 0)) * 1024 + tid * 4;
  float4 xc = *(const float4*)xwp;   // (i,f,g,o) pre-activations from input GEMM

  for (int s = 0; s < T_LEN; ++s) {
    float4 xn = make_float4(0.f, 0.f, 0.f, 0.f);
    if (s < T_LEN - 1) { xwp += delta; xn = *(const float4*)xwp; }

    // pin i/f/g gate weights into arch VGPRs for this iteration
    PINROW(wI, 0);  PINROW(wI, 8);  PINROW(wI, 16); PINROW(wI, 24);
    PINROW(wI, 32); PINROW(wI, 40); PINROW(wI, 48); PINROW(wI, 56);
    PINROW(wF, 0);  PINROW(wF, 8);  PINROW(wF, 16); PINROW(wF, 24);
    PINROW(wF, 32); PINROW(wF, 40); PINROW(wF, 48); PINROW(wF, 56);
    PINROW(wG, 0);  PINROW(wG, 8);  PINROW(wG, 16); PINROW(wG, 24);
    PINROW(wG, 32); PINROW(wG, 40); PINROW(wG, 48); PINROW(wG, 56);

    int aI = 0, aF = 0, aG = 0, aO = 0;   // 4 independent chains
    #pragma unroll
    for (int q = 0; q < 16; ++q) {
      u32 s0 = rdlane_u32(hA, 4*q+0), s1 = rdlane_u32(hA, 4*q+1),
          s2 = rdlane_u32(hA, 4*q+2), s3 = rdlane_u32(hA, 4*q+3);
      aI = sdot4(wI[4*q+0], s0, aI); aF = sdot4(wF[4*q+0], s0, aF);
      aG = sdot4(wG[4*q+0], s0, aG); aO = sdot4(wO[4*q+0], s0, aO);
      aI = sdot4(wI[4*q+1], s1, aI); aF = sdot4(wF[4*q+1], s1, aF);
      aG = sdot4(wG[4*q+1], s1, aG); aO = sdot4(wO[4*q+1], s1, aO);
      aI = sdot4(wI[4*q+2], s2, aI); aF = sdot4(wF[4*q+2], s2, aF);
      aG = sdot4(wG[4*q+2], s2, aG); aO = sdot4(wO[4*q+2], s2, aO);
      aI = sdot4(wI[4*q+3], s3, aI); aF = sdot4(wF[4*q+3], s3, aF);
      aG = sdot4(wG[4*q+3], s3, aG); aO = sdot4(wO[4*q+3], s3, aO);
    }

    float gi = fmaf((float)aI, SCALE_INV, xc.x);
    float gf = fmaf((float)aF, SCALE_INV, xc.y);
    float gc = fmaf((float)aG, SCALE_INV, xc.z);
    float go = fmaf((float)aO, SCALE_INV, xc.w);
    gi = 1.0f / (1.0f + __expf(-gi));
    gf = 1.0f / (1.0f + __expf(-gf));
    go = 1.0f / (1.0f + __expf(-go));
    gc = 1.0f - 2.0f / (__expf(2.0f * gc) + 1.0f);   // tanh
    c = gf * c + gi * gc;
    float th = 1.0f - 2.0f / (__expf(2.0f * c) + 1.0f);
    h = go * th;

    const int t = d ? (T_LEN - 1 - s) : s;
    HS[((size_t)d * T_LEN + t) * 256 + tid] = h;     // no reader in-kernel

    int hi = (int)rintf(h * HSCALE);                 // |h|<1, no clamp needed
    const int wbuf = (s + 1) & 1;
    ((unsigned char*)&H8[wbuf][0])[tid] = (unsigned char)(hi & 255);
    block_sync_lds();                                // one barrier per step
    hA = H8[wbuf][lane];
    xc = xn;
  }
}

// ---------- kernel 5: feats[t][n] = [hs_f ; hs_b]·W_out[n] + b_out[n] ----------
__global__ void feats_kernel(const float* __restrict__ hs,
                             const float* __restrict__ wout,
                             const float* __restrict__ bout,
                             float* __restrict__ feats) {
  __shared__ float lf[16 * 257];
  __shared__ float lb[16 * 257];
  const int tid = threadIdx.x;   // 128
  const int t0 = blockIdx.x * 16;
  for (int i = tid; i < 16 * 256; i += 128) {
    int r = i >> 8, k = i & 255;
    lf[r * 257 + k] = hs[(size_t)(t0 + r) * 256 + k];
    lb[r * 257 + k] = hs[(size_t)T_LEN * 256 + (size_t)(t0 + r) * 256 + k];
  }
  __syncthreads();
  const int tl = tid >> 3, n = tid & 7;
  if (n < 7) {
    float acc = bout[n];
    #pragma unroll 8
    for (int k = 0; k < 256; ++k) acc = fmaf(lf[tl * 257 + k], wout[n * 512 + k], acc);
    #pragma unroll 8
    for (int k = 0; k < 256; ++k) acc = fmaf(lb[tl * 257 + k], wout[n * 512 + 256 + k], acc);
    feats[(t0 + tl) * 7 + n] = acc;
  }
}

// ---------- kernel 6: Viterbi decode ----------
__global__ __launch_bounds__(256) void viterbi_kernel(
    const float* __restrict__ feats,
    const float* __restrict__ trans,
    float* __restrict__ out) {
  extern __shared__ char vsm[];
  float*         fe = (float*)vsm;                       // [T_LEN*7]
  unsigned char* bp = (unsigned char*)(vsm + 57344);     // [T_LEN][8]
  unsigned char* G  = (unsigned char*)(vsm + 73728);     // [32][8]
  unsigned char* bt = (unsigned char*)(vsm + 73984);     // [32]
  const int tid = threadIdx.x;

  for (int i = tid; i < T_LEN * 7; i += 256) fe[i] = feats[i];
  __syncthreads();

  if (tid < 64) {
    const int j  = tid;
    const int jc = (j < 7) ? j : 0;
    float Trow[7];
    #pragma unroll
    for (int i = 0; i < 7; ++i) Trow[i] = trans[jc * 7 + i];
    float fv = (j == 5) ? 0.0f : NEG;    // START = 5
    for (int t = 0; t < T_LEN; ++t) {
      float f0 = rdlane_f32(fv, 0), f1 = rdlane_f32(fv, 1), f2 = rdlane_f32(fv, 2),
            f3 = rdlane_f32(fv, 3), f4 = rdlane_f32(fv, 4), f5 = rdlane_f32(fv, 5),
            f6 = rdlane_f32(fv, 6);
      float v0 = f0 + Trow[0], v1 = f1 + Trow[1], v2 = f2 + Trow[2],
            v3 = f3 + Trow[3], v4 = f4 + Trow[4], v5 = f5 + Trow[5],
            v6 = f6 + Trow[6];
      bool c01 = v0 >= v1;  float m01 = c01 ? v0 : v1;  int i01 = c01 ? 0 : 1;
      bool c23 = v2 >= v3;  float m23 = c23 ? v2 : v3;  int i23 = c23 ? 2 : 3;
      bool c45 = v4 >= v5;  float m45 = c45 ? v4 : v5;  int i45 = c45 ? 4 : 5;
      bool cA  = m01 >= m23; float mA = cA ? m01 : m23; int iA = cA ? i01 : i23;
      bool cB  = m45 >= v6;  float mB = cB ? m45 : v6;  int iB = cB ? i45 : 6;
      bool cF  = mA >= mB;   float best = cF ? mA : mB; int bi = cF ? iA : iB;
      if (j < 7) bp[t * 8 + j] = (unsigned char)bi;
      fv = best + fe[t * 7 + jc];
    }
    float term = fv + trans[42 + jc];    // transitions[END=6][j]
    float best = rdlane_f32(term, 0); int btag = 0;
    #pragma unroll
    for (int i = 1; i < 7; ++i) {
      float ti = rdlane_f32(term, i);
      if (ti > best) { best = ti; btag = i; }
    }
    if (j == 0) {
      out[0] = best;
      bt[31] = (unsigned char)btag;      // tag at t = 2047
    }
  }
  __syncthreads();

  // Phase A: per-segment composed maps (32 segments x 7 entry tags)
  {
    const int s = tid >> 3, j = tid & 7;
    if (s < 32 && j < 7) {
      int g = j;
      for (int t = s * 64 + 63; t >= s * 64; --t) g = bp[t * 8 + g];
      G[s * 8 + j] = (unsigned char)g;
    }
  }
  __syncthreads();

  // Phase B: boundary tags, serial over 32 segments
  if (tid == 0) {
    int x = bt[31];
    for (int s = 31; s >= 1; --s) { x = G[s * 8 + x]; bt[s - 1] = (unsigned char)x; }
  }
  __syncthreads();

  // Phase C: parallel rewalk, one lane per segment
  if (tid < 32) {
    const int s = tid;
    int tag = bt[s];
    for (int t = s * 64 + 63; t >= s * 64; --t) {
      out[1 + t] = (float)tag;
      tag = bp[t * 8 + tag];
    }
  }
}

// ---------- host ----------
extern "C" void kernel_launch(void* const* d_in, const int* in_sizes, int n_in,
                              void* d_out, int out_size, void* d_ws, size_t ws_size,
                              hipStream_t stream) {
  const int*   words = (const int*)d_in[0];
  const float* embed = (const float*)d_in[1];
  const float* Wih_f = (const float*)d_in[2];
  const float* Whh_f = (const float*)d_in[3];
  const float* bih_f = (const float*)d_in[4];
  const float* bhh_f = (const float*)d_in[5];
  const float* Wih_b = (const float*)d_in[6];
  const float* Whh_b = (const float*)d_in[7];
  const float* bih_b = (const float*)d_in[8];
  const float* bhh_b = (const float*)d_in[9];
  const float* Wout  = (const float*)d_in[10];
  const float* bout  = (const float*)d_in[11];
  const float* trans = (const float*)d_in[12];
  const float* h0    = (const float*)d_in[13];
  const float* c0    = (const float*)d_in[14];

  float* ws = (float*)d_ws;
  float* XW = ws;                        // 2*2048*1024           = 4,194,304 f
  float* HS = ws + 4194304;              // 2*2048*256            = 1,048,576 f
  float* XS = ws + 5242880;              // 2048*256              =   524,288 f
  float* FE = ws + 5767168;              // 2048*7                =    14,336 f
  u32*   WP = (u32*)(ws + 5781504);      // 131,072 dwords (int8 weights)

  pack_whh_i8<<<512, 256, 0, stream>>>(Whh_f, Whh_b, WP);
  gather_kernel<<<T_LEN, 256, 0, stream>>>(words, embed, XS);
  dim3 ggrid(T_LEN / 32, 1024 / 128, 2);
  gemm_xw<<<ggrid, 256, 0, stream>>>(XS, Wih_f, Wih_b, bih_f, bhh_f, bih_b, bhh_b, XW);
  lstm_seq<<<2, 256, 0, stream>>>(XW, HS, WP, h0, c0);
  feats_kernel<<<128, 128, 0, stream>>>(HS, Wout, bout, FE);
  viterbi_kernel<<<1, 256, 74048, stream>>>(FE, trans, (float*)d_out);
}